// Round 7
// baseline (226.756 us; speedup 1.0000x reference)
//
#include <hip/hip_runtime.h>
#include <hip/hip_bf16.h>

// ---------------------------------------------------------------------------
// CausalSelfAttention: x[1,4096,1024] -> QKV -> 16-head causal attn -> out proj
// Round 7: attn = 8 waves x QBLK=128, each block sequentially does strip pair
//          (31-p, p) -> uniform 66 tile-units/block (no duration imbalance).
//          256 blocks, 2 heads/XCD. Static LDS addressing + dbuf from R6.
// ---------------------------------------------------------------------------

#define T_SEQ 4096
#define EMB   1024
#define NH    16
#define HD    64
#define N_QKV 3072

typedef __bf16 bf16x8 __attribute__((ext_vector_type(8)));
typedef __bf16 bf16x4 __attribute__((ext_vector_type(4)));
typedef float  f32x4  __attribute__((ext_vector_type(4)));

__device__ inline f32x4 mfma16(bf16x8 a, bf16x8 b, f32x4 c) {
    return __builtin_amdgcn_mfma_f32_16x16x32_bf16(a, b, c, 0, 0, 0);
}

__device__ inline void async_copy16(const void* g, void* l) {
    __builtin_amdgcn_global_load_lds(
        (const __attribute__((address_space(1))) unsigned int*)g,
        (__attribute__((address_space(3))) unsigned int*)l, 16, 0, 0);
}

// swizzled LDS read (used by GEMMs only)
__device__ inline bf16x8 lds_read8(const __bf16* base, int row, int colByte) {
    return *(const bf16x8*)((const char*)base + row * 128 +
                            (colByte ^ ((row & 7) << 4)));
}

// ---------------------------------------------------------------------------
// Fused prep: [0,4096) x->bf16 convert, [4096,7168) w_qkv transpose,
// [7168,8192) w_out transpose.
// ---------------------------------------------------------------------------
__global__ __launch_bounds__(256) void prep_kernel(const float* __restrict__ x,
                                                   const float* __restrict__ w_qkv,
                                                   const float* __restrict__ w_out,
                                                   __bf16* __restrict__ xb,
                                                   __bf16* __restrict__ wqkvT,
                                                   __bf16* __restrict__ woutT) {
    __shared__ __bf16 tl[32][33];
    int b = blockIdx.x;
    int t = threadIdx.x;
    if (b < 4096) {
        int i = (b * 256 + t) * 4;
        float4 v = *(const float4*)&x[i];
        bf16x4 o;
        o[0] = (__bf16)v.x; o[1] = (__bf16)v.y; o[2] = (__bf16)v.z; o[3] = (__bf16)v.w;
        *(bf16x4*)&xb[i] = o;
        return;
    }
    const float* in;
    __bf16* out;
    int N, bb;
    if (b < 7168) { bb = b - 4096; in = w_qkv; out = wqkvT; N = N_QKV; }
    else          { bb = b - 7168; in = w_out; out = woutT; N = EMB; }
    int k0 = (bb & 31) * 32, n0 = (bb >> 5) * 32;
    int r = t >> 3, c4 = (t & 7) * 4;
    float4 v = *(const float4*)&in[(size_t)(k0 + r) * N + n0 + c4];
    tl[r][c4 + 0] = (__bf16)v.x;
    tl[r][c4 + 1] = (__bf16)v.y;
    tl[r][c4 + 2] = (__bf16)v.z;
    tl[r][c4 + 3] = (__bf16)v.w;
    __syncthreads();
    bf16x4 o;
    o[0] = tl[c4 + 0][r];
    o[1] = tl[c4 + 1][r];
    o[2] = tl[c4 + 2][r];
    o[3] = tl[c4 + 3][r];
    *(bf16x4*)&out[(size_t)(n0 + r) * EMB + k0 + c4] = o;
}

// ---------------------------------------------------------------------------
// GEMM1: qkv = xb @ wqkvT^T + b_qkv. Q pre-scaled by 0.125*log2(e).
// ---------------------------------------------------------------------------
__global__ __launch_bounds__(256) void gemm_qkv_kernel(const __bf16* __restrict__ A,
                                                       const __bf16* __restrict__ Bt,
                                                       const float* __restrict__ bias,
                                                       __bf16* __restrict__ Qo,
                                                       __bf16* __restrict__ Ko,
                                                       __bf16* __restrict__ Vo) {
    const int K = EMB;
    int m0 = blockIdx.y * 128, n0 = blockIdx.x * 128;
    int tid = threadIdx.x;
    int w = tid >> 6, l = tid & 63, lg = l >> 4, lr = l & 15;
    int wr = w >> 1, wc = w & 1;

    __shared__ __align__(16) __bf16 As[128 * 32];
    __shared__ __align__(16) __bf16 Bs[128 * 32];

    f32x4 acc[4][4];
#pragma unroll
    for (int mi = 0; mi < 4; ++mi)
#pragma unroll
        for (int ni = 0; ni < 4; ++ni) acc[mi][ni] = (f32x4){0.f, 0.f, 0.f, 0.f};

    for (int k0 = 0; k0 < K; k0 += 32) {
        __syncthreads();
#pragma unroll
        for (int i = 0; i < 2; ++i) {
            int flat = tid + 256 * i;
            int row = flat >> 2, c = flat & 3;
            async_copy16(&A[(size_t)(m0 + row) * K + k0 + c * 8], As + flat * 8);
            async_copy16(&Bt[(size_t)(n0 + row) * K + k0 + c * 8], Bs + flat * 8);
        }
        __syncthreads();
        bf16x8 af[4], bfr[4];
#pragma unroll
        for (int mi = 0; mi < 4; ++mi) af[mi] = *(const bf16x8*)(As + (wr * 64 + mi * 16 + lr) * 32 + lg * 8);
#pragma unroll
        for (int ni = 0; ni < 4; ++ni) bfr[ni] = *(const bf16x8*)(Bs + (wc * 64 + ni * 16 + lr) * 32 + lg * 8);
#pragma unroll
        for (int mi = 0; mi < 4; ++mi)
#pragma unroll
            for (int ni = 0; ni < 4; ++ni)
                acc[mi][ni] = mfma16(af[mi], bfr[ni], acc[mi][ni]);
    }

    const float QSC = 0.18033688011112042f;  // 0.125 * log2(e)
#pragma unroll
    for (int mi = 0; mi < 4; ++mi) {
#pragma unroll
        for (int ni = 0; ni < 4; ++ni) {
            int n = n0 + wc * 64 + ni * 16 + lr;
            float bv = bias[n];
            int mat = n >> 10, rem = n & 1023, hh = rem >> 6, d = rem & 63;
#pragma unroll
            for (int r = 0; r < 4; ++r) {
                int mr = m0 + wr * 64 + mi * 16 + lg * 4 + r;
                float v = acc[mi][ni][r] + bv;
                size_t idx = ((size_t)hh * T_SEQ + mr) * HD + d;
                if (mat == 0)      Qo[idx] = (__bf16)(v * QSC);
                else if (mat == 1) Ko[idx] = (__bf16)v;
                else               Vo[idx] = (__bf16)v;
            }
        }
    }
}

// ---------------------------------------------------------------------------
// V [h][t][d] -> VT [h][d][t]
// ---------------------------------------------------------------------------
__global__ __launch_bounds__(256) void vt_kernel(const __bf16* __restrict__ V,
                                                 __bf16* __restrict__ VT) {
    __shared__ __bf16 tl[64][72];
    int h = blockIdx.y, t0 = blockIdx.x * 64;
    int tid = threadIdx.x;
    const __bf16* Vh = V + (size_t)h * T_SEQ * HD;
#pragma unroll
    for (int i = 0; i < 2; ++i) {
        int flat = tid + 256 * i;
        int r = flat >> 3, sl = flat & 7;
        *(bf16x8*)&tl[r][sl * 8] = *(const bf16x8*)&Vh[(size_t)(t0 + r) * HD + sl * 8];
    }
    __syncthreads();
    __bf16* VTh = VT + (size_t)h * HD * T_SEQ;
#pragma unroll
    for (int i = 0; i < 2; ++i) {
        int flat = tid + 256 * i;
        int d = flat >> 3, sl = flat & 7;
        bf16x8 o;
#pragma unroll
        for (int j = 0; j < 8; ++j) o[j] = tl[sl * 8 + j][d];
        *(bf16x8*)&VTh[(size_t)d * T_SEQ + t0 + sl * 8] = o;
    }
}

// ---------------------------------------------------------------------------
// Flash attention, causal, log2 domain. 512 threads = 8 waves x 16 q-rows
// (QBLK=128). 256 blocks; block (xcd,idx) -> head = xcd*2+(idx&1) (2 heads
// per XCD, K/V L2-resident), pair p = idx>>1. Each block sequentially
// processes strips (31-p) then (p): exactly 66 tile-units for EVERY block,
// so all 8 resident waves work until the common end (no duration imbalance).
// KV loop unrolled x2 with static buffers: LDS addresses = hoisted base+imm.
// ---------------------------------------------------------------------------
__global__ __launch_bounds__(512) void attn_kernel(const __bf16* __restrict__ Qg,
                                                   const __bf16* __restrict__ Kg,
                                                   const __bf16* __restrict__ VTg,
                                                   __bf16* __restrict__ Og) {
    __shared__ __align__(16) __bf16 Ks[2][64 * 64];   // +8192B between bufs
    __shared__ __align__(16) __bf16 Vs[2][64 * 64];
    __shared__ __align__(16) __bf16 Ps[8][16 * 64];   // 2048B per wave

    const int bid = blockIdx.x;
    const int xcd = bid & 7, idx = bid >> 3;
    const int h = xcd * 2 + (idx & 1);   // 2 heads per XCD
    const int p = idx >> 1;              // 0..15 -> strips (31-p, p)
    const int tid = threadIdx.x;
    const int w = tid >> 6, l = tid & 63, lg = l >> 4, lr = l & 15;

    const __bf16* Qh = Qg + (size_t)h * T_SEQ * HD;
    const __bf16* Kh = Kg + (size_t)h * T_SEQ * HD;
    const __bf16* Vh = VTg + (size_t)h * HD * T_SEQ;

    // staging: 512 lanes x 16B = one full 64x64 bf16 tile per issue
    const int srow = tid >> 3, sslot = tid & 7;
    const int sB = (sslot * 16) ^ ((srow & 7) << 4);
    const size_t kOffB = (size_t)srow * HD + (sB >> 1);
    const size_t vOffB = (size_t)srow * T_SEQ + (sB >> 1);

    // loop-invariant LDS bases (byte pointers); buf -> +8192, blk/n -> +2048
    const int coff0 = (lg * 16) ^ ((lr & 7) << 4);
    const int coff1 = coff0 ^ 64;
    const char* KB0 = (const char*)Ks + lr * 128 + coff0;
    const char* KB1 = (const char*)Ks + lr * 128 + coff1;
    const char* VB0 = (const char*)Vs + lr * 128 + coff0;
    const char* VB1 = (const char*)Vs + lr * 128 + coff1;
    char* PW = (char*)Ps + w * 2048 + lr * 128;
    const char* PA0 = PW + coff0;
    const char* PA1 = PW + coff1;
    char* pwr0 = PW + ((0  + 8 * lg) ^ ((lr & 7) << 4));
    char* pwr1 = PW + ((32 + 8 * lg) ^ ((lr & 7) << 4));
    char* pwr2 = PW + ((64 + 8 * lg) ^ ((lr & 7) << 4));
    char* pwr3 = PW + ((96 + 8 * lg) ^ ((lr & 7) << 4));

#define ATTN_STAGE(BUF)                                          \
    do {                                                         \
        async_copy16(kSrc, &Ks[BUF][tid * 8]);                   \
        async_copy16(vSrc, &Vs[BUF][tid * 8]);                   \
        kSrc += 64 * HD;                                         \
        vSrc += 64;                                              \
    } while (0)

#define ATTN_TILE(BUF, KV0)                                                       \
    if ((KV0) <= qr0 + 15) {                                                      \
        bf16x8 kf[4][2];                                                          \
        _Pragma("unroll") for (int blk = 0; blk < 4; ++blk) {                     \
            kf[blk][0] = *(const bf16x8*)(KB0 + (BUF) * 8192 + blk * 2048);       \
            kf[blk][1] = *(const bf16x8*)(KB1 + (BUF) * 8192 + blk * 2048);       \
        }                                                                         \
        __builtin_amdgcn_s_setprio(1);                                            \
        f32x4 s[4];                                                               \
        _Pragma("unroll") for (int blk = 0; blk < 4; ++blk) {                     \
            f32x4 a = (f32x4){0.f, 0.f, 0.f, 0.f};                                \
            a = mfma16(kf[blk][0], qf[0], a);                                     \
            a = mfma16(kf[blk][1], qf[1], a);                                     \
            s[blk] = a;                                                           \
        }                                                                         \
        __builtin_amdgcn_s_setprio(0);                                            \
        float mx = -1e30f;                                                        \
        if ((KV0) + 63 > qr0) {                                                   \
            _Pragma("unroll") for (int blk = 0; blk < 4; ++blk)                   \
                _Pragma("unroll") for (int r = 0; r < 4; ++r) {                   \
                    int kv = (KV0) + 16 * blk + 4 * lg + r;                       \
                    float sv = (kv <= qr0 + lr) ? s[blk][r] : -1e30f;             \
                    s[blk][r] = sv;                                               \
                    mx = fmaxf(mx, sv);                                           \
                }                                                                 \
        } else {                                                                  \
            _Pragma("unroll") for (int blk = 0; blk < 4; ++blk)                   \
                _Pragma("unroll") for (int r = 0; r < 4; ++r)                     \
                    mx = fmaxf(mx, s[blk][r]);                                    \
        }                                                                         \
        if (!__all(mx <= m + 8.f)) {                                              \
            float mf = fmaxf(mx, __shfl_xor(mx, 16, 64));                         \
            mf = fmaxf(mf, __shfl_xor(mf, 32, 64));                               \
            float mnew = fmaxf(m, mf);                                            \
            float alpha = exp2f(m - mnew);                                        \
            m = mnew;                                                             \
            lsum *= alpha;                                                        \
            float ar[4];                                                          \
            _Pragma("unroll") for (int r = 0; r < 4; ++r)                         \
                ar[r] = __shfl(alpha, 4 * lg + r, 64);                            \
            _Pragma("unroll") for (int n = 0; n < 4; ++n)                         \
                _Pragma("unroll") for (int r = 0; r < 4; ++r)                     \
                    oacc[n][r] *= ar[r];                                          \
        }                                                                         \
        {                                                                         \
            float ps = 0.f;                                                       \
            bf16x4 pk0, pk1, pk2, pk3;                                            \
            _Pragma("unroll") for (int r = 0; r < 4; ++r) {                       \
                float p0 = exp2f(s[0][r] - m); ps += p0; pk0[r] = (__bf16)p0;     \
                float p1 = exp2f(s[1][r] - m); ps += p1; pk1[r] = (__bf16)p1;     \
                float p2 = exp2f(s[2][r] - m); ps += p2; pk2[r] = (__bf16)p2;     \
                float p3 = exp2f(s[3][r] - m); ps += p3; pk3[r] = (__bf16)p3;     \
            }                                                                     \
            *(bf16x4*)pwr0 = pk0;                                                 \
            *(bf16x4*)pwr1 = pk1;                                                 \
            *(bf16x4*)pwr2 = pk2;                                                 \
            *(bf16x4*)pwr3 = pk3;                                                 \
            lsum += ps;                                                           \
        }                                                                         \
        {                                                                         \
            bf16x8 pa0 = *(const bf16x8*)PA0;                                     \
            bf16x8 pa1 = *(const bf16x8*)PA1;                                     \
            __builtin_amdgcn_s_setprio(1);                                        \
            _Pragma("unroll") for (int n = 0; n < 4; ++n) {                       \
                bf16x8 vb0 = *(const bf16x8*)(VB0 + (BUF) * 8192 + n * 2048);     \
                bf16x8 vb1 = *(const bf16x8*)(VB1 + (BUF) * 8192 + n * 2048);     \
                oacc[n] = mfma16(pa0, vb0, oacc[n]);                              \
                oacc[n] = mfma16(pa1, vb1, oacc[n]);                              \
            }                                                                     \
            __builtin_amdgcn_s_setprio(0);                                        \
        }                                                                         \
    }

#pragma unroll 1
    for (int sp = 0; sp < 2; ++sp) {
        const int S = sp ? p : (31 - p);       // heavy strip first
        const int qr0 = S * 128 + 16 * w;

        const __bf16* kSrc = Kh + kOffB;
        const __bf16* vSrc = Vh + vOffB;

        bf16x8 qf[2];
#pragma unroll
        for (int kd = 0; kd < 2; ++kd)
            qf[kd] = *(const bf16x8*)&Qh[(size_t)(qr0 + lr) * HD + kd * 32 + lg * 8];

        f32x4 oacc[4];
#pragma unroll
        for (int n = 0; n < 4; ++n) oacc[n] = (f32x4){0.f, 0.f, 0.f, 0.f};
        float m = -1e30f, lsum = 0.f;

        const int ntiles = 2 * S + 2;  // always even

        ATTN_STAGE(0);
        __syncthreads();

        for (int t = 0; t < ntiles; t += 2) {
            ATTN_STAGE(1);            // tile t+1 (exists: ntiles even)
            ATTN_TILE(0, t * 64)
            __syncthreads();          // drains buf1 loads; frees buf0
            if (t + 2 < ntiles) ATTN_STAGE(0);  // tile t+2
            ATTN_TILE(1, (t + 1) * 64)
            __syncthreads();          // drains buf0 loads; frees buf1
        }

        // final cross-lane reduction of row-sum partials
        lsum += __shfl_xor(lsum, 16, 64);
        lsum += __shfl_xor(lsum, 32, 64);
        float linv = 1.0f / lsum;
        float lrv[4];
#pragma unroll
        for (int r = 0; r < 4; ++r) lrv[r] = __shfl(linv, 4 * lg + r, 64);
#pragma unroll
        for (int n = 0; n < 4; ++n)
#pragma unroll
            for (int r = 0; r < 4; ++r) {
                int q = qr0 + 4 * lg + r;
                Og[(size_t)q * EMB + h * HD + 16 * n + lr] = (__bf16)(oacc[n][r] * lrv[r]);
            }
    }

#undef ATTN_STAGE
#undef ATTN_TILE
}

// ---------------------------------------------------------------------------
// GEMM2: out = AO @ woutT^T + b_out (fp32 out)
// ---------------------------------------------------------------------------
__global__ __launch_bounds__(256) void gemm_out_kernel(const __bf16* __restrict__ A,
                                                       const __bf16* __restrict__ Bt,
                                                       const float* __restrict__ bias,
                                                       float* __restrict__ out) {
    const int K = EMB;
    int m0 = blockIdx.y * 128, n0 = blockIdx.x * 128;
    int tid = threadIdx.x;
    int w = tid >> 6, l = tid & 63, lg = l >> 4, lr = l & 15;
    int wr = w >> 1, wc = w & 1;

    __shared__ __align__(16) __bf16 As[128 * 32];
    __shared__ __align__(16) __bf16 Bs[128 * 32];

    f32x4 acc[4][4];
#pragma unroll
    for (int mi = 0; mi < 4; ++mi)
#pragma unroll
        for (int ni = 0; ni < 4; ++ni) acc[mi][ni] = (f32x4){0.f, 0.f, 0.f, 0.f};

    for (int k0 = 0; k0 < K; k0 += 32) {
        __syncthreads();
#pragma unroll
        for (int i = 0; i < 2; ++i) {
            int flat = tid + 256 * i;
            int row = flat >> 2, c = flat & 3;
            async_copy16(&A[(size_t)(m0 + row) * K + k0 + c * 8], As + flat * 8);
            async_copy16(&Bt[(size_t)(n0 + row) * K + k0 + c * 8], Bs + flat * 8);
        }
        __syncthreads();
        bf16x8 af[4], bfr[4];
#pragma unroll
        for (int mi = 0; mi < 4; ++mi) af[mi] = *(const bf16x8*)(As + (wr * 64 + mi * 16 + lr) * 32 + lg * 8);
#pragma unroll
        for (int ni = 0; ni < 4; ++ni) bfr[ni] = *(const bf16x8*)(Bs + (wc * 64 + ni * 16 + lr) * 32 + lg * 8);
#pragma unroll
        for (int mi = 0; mi < 4; ++mi)
#pragma unroll
            for (int ni = 0; ni < 4; ++ni)
                acc[mi][ni] = mfma16(af[mi], bfr[ni], acc[mi][ni]);
    }

#pragma unroll
    for (int mi = 0; mi < 4; ++mi) {
#pragma unroll
        for (int ni = 0; ni < 4; ++ni) {
            int n = n0 + wc * 64 + ni * 16 + lr;
            float bv = bias[n];
#pragma unroll
            for (int r = 0; r < 4; ++r) {
                int mr = m0 + wr * 64 + mi * 16 + lg * 4 + r;
                out[(size_t)mr * EMB + n] = acc[mi][ni][r] + bv;
            }
        }
    }
}

// ---------------------------------------------------------------------------
extern "C" void kernel_launch(void* const* d_in, const int* in_sizes, int n_in,
                              void* d_out, int out_size, void* d_ws, size_t ws_size,
                              hipStream_t stream) {
    const float* x      = (const float*)d_in[0];
    const float* w_qkv  = (const float*)d_in[1];
    const float* b_qkv  = (const float*)d_in[2];
    const float* w_out  = (const float*)d_in[3];
    const float* b_out  = (const float*)d_in[4];
    float* out = (float*)d_out;

    char* ws = (char*)d_ws;
    __bf16* xb    = (__bf16*)(ws);                      // 8 MiB, reused as AO
    __bf16* AO    = (__bf16*)(ws);
    __bf16* wqkvT = (__bf16*)(ws + ((size_t)8 << 20));  // 6 MiB
    __bf16* woutT = (__bf16*)(ws + ((size_t)14 << 20)); // 2 MiB
    __bf16* Qh    = (__bf16*)(ws + ((size_t)16 << 20)); // 8 MiB
    __bf16* Kh    = (__bf16*)(ws + ((size_t)24 << 20)); // 8 MiB
    __bf16* Vh    = (__bf16*)(ws + ((size_t)32 << 20)); // 8 MiB
    __bf16* VTh   = (__bf16*)(ws + ((size_t)40 << 20)); // 8 MiB

    prep_kernel<<<dim3(8192), 256, 0, stream>>>(x, w_qkv, w_out, xb, wqkvT, woutT);

    gemm_qkv_kernel<<<dim3(N_QKV / 128, T_SEQ / 128), 256, 0, stream>>>(xb, wqkvT, b_qkv, Qh, Kh, Vh);

    vt_kernel<<<dim3(T_SEQ / 64, NH), 256, 0, stream>>>(Vh, VTh);

    attn_kernel<<<dim3(256), 512, 0, stream>>>(Qh, Kh, VTh, AO);

    gemm_out_kernel<<<dim3(EMB / 128, T_SEQ / 128), 256, 0, stream>>>(AO, woutT, b_out, out);
}